// Round 6
// baseline (44.701 us; speedup 1.0000x reference)
//
#include <hip/hip_runtime.h>
#include <math.h>

namespace {

constexpr int Bn = 2, Hn = 128, Wn = 128, Cn = 256, Vn = 64;

__device__ __forceinline__ void load8(float* r, const float* p) {
    float4 a = *(const float4*)(p);
    float4 b = *(const float4*)(p + 4);
    r[0]=a.x; r[1]=a.y; r[2]=a.z; r[3]=a.w;
    r[4]=b.x; r[5]=b.y; r[6]=b.z; r[7]=b.w;
}

// 256 thr = 16 pixel-PAIRS x 16 channel-splits. Lane owns 2 adjacent pixels
// x 16 ch. R4 analysis: L1 data path bound (~1.05 GB through L1, 64B/cyc/CU
// -> ~28us floor). Pairing shares the 6 ref columns between both pixels:
// score traffic 838->503 MB, value 210->126 MB. Skeleton stays R4's rolled-di
// online softmax (proved 72 VGPR); pairing adds ~35 regs -> ~110, 4 waves/
// SIMD = grid-provided 4096 waves. cc passes are explicit static blocks so
// every array index is compile-time (no scratch). No forced launch bounds.
__global__ __launch_bounds__(256)
void local_attn_kernel(const float* __restrict__ mainp,
                       const float* __restrict__ mainv,
                       const float* __restrict__ refp,
                       const float* __restrict__ refv,
                       float* __restrict__ outp)
{
    const int t = threadIdx.x;
    const int s = t & 15;       // channel/value split 0..15
    const int g = t >> 4;       // pixel-pair 0..15
    const int blk = blockIdx.x; // 0 .. 1023
    const int seg = blk & 3;
    const int h   = (blk >> 2) & (Hn - 1);
    const int b   = blk >> 9;
    const int w0  = seg * 32 + g * 2;   // px0 = w0, px1 = w0+1
    const int rowbase = b * Hn + h;
    const int colbase = w0 - 2;         // columns colbase .. colbase+5

    // main channels for both pixels: 16 ch each (s*8 and 128+s*8)
    float m0[16], m1[16];
    const float* mp = mainp + ((size_t)rowbase * Wn + w0) * Cn + s * 8;
    load8(m0,     mp);
    load8(m0 + 8, mp + 128);
    load8(m1,     mp + Cn);
    load8(m1 + 8, mp + Cn + 128);

    // self scores (slot 25): full dot via 4-step shuffle reduce
    float self0 = 0.f, self1 = 0.f;
    #pragma unroll
    for (int c = 0; c < 16; ++c) {
        self0 = fmaf(m0[c], m0[c], self0);
        self1 = fmaf(m1[c], m1[c], self1);
    }
    #pragma unroll
    for (int k = 1; k < 16; k <<= 1) {
        self0 += __shfl_xor(self0, k);
        self1 += __shfl_xor(self1, k);
    }

    // online-softmax state seeded with the self slot (weight exp(0)=1)
    float mx0 = self0, mx1 = self1, den0 = 1.f, den1 = 1.f;
    float acc0[4], acc1[4];
    {
        const float* mvp = mainv + ((size_t)rowbase * Wn + w0) * Vn + s * 4;
        float4 a = *(const float4*)(mvp);
        float4 c = *(const float4*)(mvp + Vn);
        acc0[0]=a.x; acc0[1]=a.y; acc0[2]=a.z; acc0[3]=a.w;
        acc1[0]=c.x; acc1[1]=c.y; acc1[2]=c.z; acc1[3]=c.w;
    }

    #pragma unroll 1
    for (int di = 0; di < 5; ++di) {
        const int hh = h + di - 2;
        const bool rowok = (unsigned)hh < (unsigned)Hn;
        const size_t rbase = (size_t)(b * Hn + (rowok ? hh : 0)) * Wn;
        const float* rp = refp + rbase * Cn + s * 8;

        float sc0[5] = {0.f,0.f,0.f,0.f,0.f};
        float sc1[5] = {0.f,0.f,0.f,0.f,0.f};

        // ---- cc = 0 pass: channels s*8..s*8+7, shared column loads
        #pragma unroll
        for (int o = 0; o < 6; ++o) {
            const int col = colbase + o;
            const bool ok = rowok && (unsigned)col < (unsigned)Wn;
            float r[8];
            #pragma unroll
            for (int c = 0; c < 8; ++c) r[c] = 0.f;
            if (ok) load8(r, rp + (size_t)col * Cn);
            if (o < 5) {
                float a = 0.f;
                #pragma unroll
                for (int c = 0; c < 8; ++c) a = fmaf(m0[c], r[c], a);
                sc0[o] += a;
            }
            if (o >= 1) {
                float a = 0.f;
                #pragma unroll
                for (int c = 0; c < 8; ++c) a = fmaf(m1[c], r[c], a);
                sc1[o - 1] += a;
            }
        }
        // ---- cc = 1 pass: channels 128+s*8 ..
        #pragma unroll
        for (int o = 0; o < 6; ++o) {
            const int col = colbase + o;
            const bool ok = rowok && (unsigned)col < (unsigned)Wn;
            float r[8];
            #pragma unroll
            for (int c = 0; c < 8; ++c) r[c] = 0.f;
            if (ok) load8(r, rp + (size_t)col * Cn + 128);
            if (o < 5) {
                float a = 0.f;
                #pragma unroll
                for (int c = 0; c < 8; ++c) a = fmaf(m0[8 + c], r[c], a);
                sc0[o] += a;
            }
            if (o >= 1) {
                float a = 0.f;
                #pragma unroll
                for (int c = 0; c < 8; ++c) a = fmaf(m1[8 + c], r[c], a);
                sc1[o - 1] += a;
            }
        }

        // reduce partial dots across the 16 split lanes (lane bits 0..3)
        #pragma unroll
        for (int k = 0; k < 5; ++k) {
            float v0 = sc0[k], v1 = sc1[k];
            v0 += __shfl_xor(v0, 1); v0 += __shfl_xor(v0, 2);
            v0 += __shfl_xor(v0, 4); v0 += __shfl_xor(v0, 8);
            v1 += __shfl_xor(v1, 1); v1 += __shfl_xor(v1, 2);
            v1 += __shfl_xor(v1, 4); v1 += __shfl_xor(v1, 8);
            sc0[k] = v0; sc1[k] = v1;
        }

        // ---- online softmax row update (both pixels)
        const float rm0 = fmaxf(fmaxf(fmaxf(sc0[0], sc0[1]), fmaxf(sc0[2], sc0[3])), sc0[4]);
        const float rm1 = fmaxf(fmaxf(fmaxf(sc1[0], sc1[1]), fmaxf(sc1[2], sc1[3])), sc1[4]);
        const float nm0 = fmaxf(mx0, rm0), nm1 = fmaxf(mx1, rm1);
        const float e0 = __expf(mx0 - nm0), e1 = __expf(mx1 - nm1);
        float wk0[5], wk1[5];
        float sum0 = 0.f, sum1 = 0.f;
        #pragma unroll
        for (int k = 0; k < 5; ++k) {
            wk0[k] = __expf(sc0[k] - nm0); sum0 += wk0[k];
            wk1[k] = __expf(sc1[k] - nm1); sum1 += wk1[k];
        }
        den0 = den0 * e0 + sum0;
        den1 = den1 * e1 + sum1;
        #pragma unroll
        for (int c = 0; c < 4; ++c) { acc0[c] *= e0; acc1[c] *= e1; }
        mx0 = nm0; mx1 = nm1;

        // ---- fused value row: shared column loads (lane owns V ch s*4..+3)
        const float* rvp = refv + rbase * Vn + s * 4;
        #pragma unroll
        for (int o = 0; o < 6; ++o) {
            const int col = colbase + o;
            float4 rv = make_float4(0.f, 0.f, 0.f, 0.f);
            if (rowok && (unsigned)col < (unsigned)Wn)
                rv = *(const float4*)(rvp + (size_t)col * Vn);
            if (o < 5) {
                const float wkj = wk0[o];
                acc0[0] = fmaf(wkj, rv.x, acc0[0]);
                acc0[1] = fmaf(wkj, rv.y, acc0[1]);
                acc0[2] = fmaf(wkj, rv.z, acc0[2]);
                acc0[3] = fmaf(wkj, rv.w, acc0[3]);
            }
            if (o >= 1) {
                const float wkj = wk1[o - 1];
                acc1[0] = fmaf(wkj, rv.x, acc1[0]);
                acc1[1] = fmaf(wkj, rv.y, acc1[1]);
                acc1[2] = fmaf(wkj, rv.z, acc1[2]);
                acc1[3] = fmaf(wkj, rv.w, acc1[3]);
            }
        }
    }

    const float inv0 = 1.f / den0, inv1 = 1.f / den1;
    float* op = outp + ((size_t)rowbase * Wn + w0) * Vn + s * 4;
    float4 o0, o1;
    o0.x = acc0[0]*inv0; o0.y = acc0[1]*inv0; o0.z = acc0[2]*inv0; o0.w = acc0[3]*inv0;
    o1.x = acc1[0]*inv1; o1.y = acc1[1]*inv1; o1.z = acc1[2]*inv1; o1.w = acc1[3]*inv1;
    *(float4*)(op)      = o0;
    *(float4*)(op + Vn) = o1;
}

} // namespace

extern "C" void kernel_launch(void* const* d_in, const int* in_sizes, int n_in,
                              void* d_out, int out_size, void* d_ws, size_t ws_size,
                              hipStream_t stream)
{
    const float* mainp = (const float*)d_in[0];
    const float* mainv = (const float*)d_in[1];
    const float* refp  = (const float*)d_in[2];
    const float* refv  = (const float*)d_in[3];
    float* outp = (float*)d_out;

    dim3 grid(Bn * Hn * 4);   // 1024 blocks: one per 32-pixel row segment
    dim3 block(256);          // 16 pairs x 16 splits
    hipLaunchKernelGGL(local_attn_kernel, grid, block, 0, stream,
                       mainp, mainv, refp, refv, outp);
}